// Round 1
// baseline (3131.669 us; speedup 1.0000x reference)
//
#include <hip/hip_runtime.h>

#define T_SEQ 2048
#define BT    8192
#define DM    512
#define NR    8
#define NSTEP 5
#define K1    1536   // 3*D
#define H2    1024   // 2*D
#define VSZ   32000

using ushort_t = unsigned short;
using bf16x8 = __attribute__((ext_vector_type(8))) __bf16;
using f32x4  = __attribute__((ext_vector_type(4))) float;

__device__ __forceinline__ ushort_t f2bf(float f) {
    union { float f; unsigned u; } v; v.f = f;
    unsigned r = v.u + 0x7FFFu + ((v.u >> 16) & 1u);
    return (ushort_t)(r >> 16);
}

__device__ __forceinline__ void gload16(const void* g, void* l) {
    __builtin_amdgcn_global_load_lds((const __attribute__((address_space(1))) void*)g,
                                     (__attribute__((address_space(3))) void*)l, 16, 0, 0);
}

// transpose f32 src[z][K][N] -> bf16 dst[z*dstBatch + n*dstRow + k]
__global__ void transpose_f32_bf16(const float* __restrict__ src, ushort_t* __restrict__ dst,
                                   int K, int N, long long srcBatch, long long dstBatch, int dstRow)
{
    __shared__ float tile[32][33];
    src += (size_t)blockIdx.z * srcBatch;
    dst += (size_t)blockIdx.z * dstBatch;
    int n0 = blockIdx.x * 32, k0 = blockIdx.y * 32;
    int tx = threadIdx.x, ty = threadIdx.y;
    #pragma unroll
    for (int i = 0; i < 32; i += 8)
        tile[ty + i][tx] = src[(size_t)(k0 + ty + i) * N + (n0 + tx)];
    __syncthreads();
    #pragma unroll
    for (int i = 0; i < 32; i += 8)
        dst[(size_t)(n0 + ty + i) * dstRow + (k0 + tx)] = f2bf(tile[tx][ty + i]);
}

__global__ void embed_pos(const int* __restrict__ tokens, const float* __restrict__ emb,
                          const float* __restrict__ pos, float* __restrict__ x)
{
    int row = blockIdx.x;
    int t = row & (T_SEQ - 1);
    int tok = tokens[row];
    const float2* e = (const float2*)(emb + (size_t)tok * DM);
    const float2* p = (const float2*)(pos + (size_t)t * DM);
    float2* xo = (float2*)(x + (size_t)row * DM);
    int i = threadIdx.x;              // 256 threads, 256 float2 = 512 floats
    float2 ev = e[i], pv = p[i];
    xo[i] = make_float2(ev.x + pv.x, ev.y + pv.y);
}

__global__ void rw_kernel(const float* __restrict__ gate, const float* __restrict__ selw,
                          const float* __restrict__ selb, float* __restrict__ rw)
{
    int t = blockIdx.x, lane = threadIdx.x;  // 64 lanes
    float p[NR];
    #pragma unroll
    for (int r = 0; r < NR; ++r) p[r] = 0.f;
    for (int d = lane; d < DM; d += 64) {
        float gv = gate[(size_t)t * DM + d] * 0.001f;
        const float* swr = selw + (size_t)d * NR;
        #pragma unroll
        for (int r = 0; r < NR; ++r) p[r] += gv * swr[r];
    }
    #pragma unroll
    for (int o = 32; o; o >>= 1) {
        #pragma unroll
        for (int r = 0; r < NR; ++r) p[r] += __shfl_down(p[r], o, 64);
    }
    if (lane == 0) {
        float mx = -1e30f;
        #pragma unroll
        for (int r = 0; r < NR; ++r) { p[r] += selb[r]; mx = fmaxf(mx, p[r]); }
        float s = 0.f;
        #pragma unroll
        for (int r = 0; r < NR; ++r) { p[r] = expf(p[r] - mx); s += p[r]; }
        float inv = 1.0f / s;
        #pragma unroll
        for (int r = 0; r < NR; ++r) rw[t * NR + r] = p[r] * inv;
    }
}

// NB[row][0:512]=x[row], [512:1024]=x[left], [1024:1536]=x[right], bf16
__global__ void nb_build(const float* __restrict__ x, ushort_t* __restrict__ nbuf)
{
    int row = blockIdx.x;
    int t = row & (T_SEQ - 1), b = row >> 11;
    int c = threadIdx.x * 8;          // 192 threads * 8 = 1536
    int seg = c >> 9, off = c & 511;
    int srow = (seg == 0) ? row
             : (seg == 1) ? ((b << 11) | ((t + T_SEQ - 1) & (T_SEQ - 1)))
                          : ((b << 11) | ((t + 1) & (T_SEQ - 1)));
    const float* s = x + (size_t)srow * DM + off;
    float4 f0 = *(const float4*)s;
    float4 f1 = *(const float4*)(s + 4);
    ushort_t tmp[8] = { f2bf(f0.x), f2bf(f0.y), f2bf(f0.z), f2bf(f0.w),
                        f2bf(f1.x), f2bf(f1.y), f2bf(f1.z), f2bf(f1.w) };
    *(uint4*)&nbuf[(size_t)row * K1 + c] = *(const uint4*)tmp;
}

// FINAL=0: x = LN(x + ev + sum_r rw*b2) * g + b   (in-place f32)
// FINAL=1: xbf = bf16(LN(x) * g + b)
template<int FINAL>
__global__ void ln_kernel(const float* __restrict__ xin, const float* __restrict__ ev,
                          const float* __restrict__ b2, const float* __restrict__ rwp,
                          const float* __restrict__ g, const float* __restrict__ b,
                          float* __restrict__ xout, ushort_t* __restrict__ xbf)
{
    __shared__ float sA[4], sB[4];
    int row = blockIdx.x, t = row & (T_SEQ - 1);
    int d = threadIdx.x << 1;
    float2 v = *(const float2*)(xin + (size_t)row * DM + d);
    float s0 = v.x, s1 = v.y;
    if (!FINAL) {
        float2 e = *(const float2*)(ev + (size_t)row * DM + d);
        s0 += e.x; s1 += e.y;
        #pragma unroll
        for (int r = 0; r < NR; ++r) {
            float w = rwp[t * NR + r];
            s0 += w * b2[r * DM + d];
            s1 += w * b2[r * DM + d + 1];
        }
    }
    float sum = s0 + s1, sq = s0 * s0 + s1 * s1;
    #pragma unroll
    for (int o = 32; o; o >>= 1) {
        sum += __shfl_down(sum, o, 64);
        sq  += __shfl_down(sq, o, 64);
    }
    int w = threadIdx.x >> 6;
    if ((threadIdx.x & 63) == 0) { sA[w] = sum; sB[w] = sq; }
    __syncthreads();
    sum = sA[0] + sA[1] + sA[2] + sA[3];
    sq  = sB[0] + sB[1] + sB[2] + sB[3];
    float mean = sum * (1.0f / DM);
    float var  = sq * (1.0f / DM) - mean * mean;
    float rstd = rsqrtf(var + 1e-5f);
    float o0 = (s0 - mean) * rstd * g[d] + b[d];
    float o1 = (s1 - mean) * rstd * g[d + 1] + b[d + 1];
    if (FINAL) {
        xbf[(size_t)row * DM + d]     = f2bf(o0);
        xbf[(size_t)row * DM + d + 1] = f2bf(o1);
    } else {
        *(float2*)(xout + (size_t)row * DM + d) = make_float2(o0, o1);
    }
}

// C[M,N] = A[M,K] @ B[K,N], A row-major bf16 (lda), Bt = B^T row-major bf16 (ldb).
// 128x128 tile, BK=64, 4 waves, global_load_lds staging, XOR k-slot swizzle.
// EPI 0: Cf = acc (f32). EPI 1: Cb = bf16(gelu(acc + b1[r][h]) * rw[t][r]).
// EPI 2: Cf = (accumulate? Cf : 0) + acc.
template<int EPI>
__global__ __launch_bounds__(256)
void gemm_bt(const ushort_t* __restrict__ A, const ushort_t* __restrict__ Bt,
             float* __restrict__ Cf, ushort_t* __restrict__ Cb,
             int M, int N, int K, int lda, int ldb, int ldc,
             const float* __restrict__ bias, const float* __restrict__ rwp,
             int colOffset, int accumulate)
{
    __shared__ ushort_t Alds[128 * 64];
    __shared__ ushort_t Blds[128 * 64];
    const int tid = threadIdx.x;
    const int wave = tid >> 6, lane = tid & 63;
    const int wm = wave >> 1, wn = wave & 1;
    const int rowBase = blockIdx.y * 128;
    const int colBase = blockIdx.x * 128;

    // staging: chunk (wave*4+j) covers rows chunk*8..+8, lane -> row chunk*8+(lane>>3),
    // physical k-slot lane&7; source k-slot pre-swizzled so reads can XOR by (row&7).
    const int srow = wave * 32 + (lane >> 3);
    const int sk   = (((lane & 7) ^ ((lane >> 3) & 7)) << 3);
    const ushort_t* Ag = A  + (size_t)(rowBase + srow) * lda + sk;
    const ushort_t* Bg = Bt + (size_t)(colBase + srow) * ldb + sk;

    f32x4 acc[4][4] = {};

    for (int kt = 0; kt < K; kt += 64) {
        __syncthreads();
        #pragma unroll
        for (int j = 0; j < 4; ++j)
            gload16(Ag + (size_t)(j * 8) * lda + kt, &Alds[(wave * 4 + j) * 512]);
        #pragma unroll
        for (int j = 0; j < 4; ++j)
            gload16(Bg + (size_t)(j * 8) * ldb + kt, &Blds[(wave * 4 + j) * 512]);
        __syncthreads();

        #pragma unroll
        for (int kk = 0; kk < 2; ++kk) {
            bf16x8 af[4], bfr[4];
            #pragma unroll
            for (int m = 0; m < 4; ++m) {
                int row = wm * 64 + m * 16 + (lane & 15);
                int slot = (kk * 4 + (lane >> 4)) ^ (row & 7);
                af[m] = *(const bf16x8*)&Alds[row * 64 + slot * 8];
            }
            #pragma unroll
            for (int n = 0; n < 4; ++n) {
                int row = wn * 64 + n * 16 + (lane & 15);
                int slot = (kk * 4 + (lane >> 4)) ^ (row & 7);
                bfr[n] = *(const bf16x8*)&Blds[row * 64 + slot * 8];
            }
            #pragma unroll
            for (int m = 0; m < 4; ++m)
                #pragma unroll
                for (int n = 0; n < 4; ++n)
                    acc[m][n] = __builtin_amdgcn_mfma_f32_16x16x32_bf16(af[m], bfr[n], acc[m][n], 0, 0, 0);
        }
    }

    const int cl = lane & 15, rl = (lane >> 4) << 2;
    if constexpr (EPI == 0) {
        #pragma unroll
        for (int m = 0; m < 4; ++m) {
            int gr = rowBase + wm * 64 + m * 16 + rl;
            #pragma unroll
            for (int n = 0; n < 4; ++n) {
                int gc = colBase + wn * 64 + n * 16 + cl;
                #pragma unroll
                for (int i = 0; i < 4; ++i)
                    Cf[(size_t)(gr + i) * ldc + gc] = acc[m][n][i];
            }
        }
    } else if constexpr (EPI == 1) {
        #pragma unroll
        for (int m = 0; m < 4; ++m) {
            int gr = rowBase + wm * 64 + m * 16 + rl;
            #pragma unroll
            for (int n = 0; n < 4; ++n) {
                int gc = colBase + wn * 64 + n * 16 + cl;
                int fullcol = colOffset + gc;
                int r = fullcol >> 10, h = fullcol & (H2 - 1);
                float bv = bias[r * H2 + h];
                #pragma unroll
                for (int i = 0; i < 4; ++i) {
                    int grow = gr + i;
                    float vv = acc[m][n][i] + bv;
                    vv = 0.5f * vv * (1.0f + erff(vv * 0.70710678118654752f));
                    vv *= rwp[(grow & (T_SEQ - 1)) * NR + r];
                    Cb[(size_t)grow * ldc + gc] = f2bf(vv);
                }
            }
        }
    } else {
        #pragma unroll
        for (int m = 0; m < 4; ++m) {
            int gr = rowBase + wm * 64 + m * 16 + rl;
            #pragma unroll
            for (int n = 0; n < 4; ++n) {
                int gc = colBase + wn * 64 + n * 16 + cl;
                #pragma unroll
                for (int i = 0; i < 4; ++i) {
                    size_t idx = (size_t)(gr + i) * ldc + gc;
                    float vv = acc[m][n][i];
                    Cf[idx] = accumulate ? (Cf[idx] + vv) : vv;
                }
            }
        }
    }
}

static inline int imin_host(int a, int b) { return a < b ? a : b; }

extern "C" void kernel_launch(void* const* d_in, const int* in_sizes, int n_in,
                              void* d_out, int out_size, void* d_ws, size_t ws_size,
                              hipStream_t stream)
{
    const int*   tokens = (const int*)d_in[0];
    const float* gate   = (const float*)d_in[1];
    const float* emb    = (const float*)d_in[2];
    const float* pos    = (const float*)d_in[3];
    const float* w1     = (const float*)d_in[4];
    const float* b1     = (const float*)d_in[5];
    const float* w2     = (const float*)d_in[6];
    const float* b2     = (const float*)d_in[7];
    const float* selw   = (const float*)d_in[8];
    const float* selb   = (const float*)d_in[9];
    const float* ng     = (const float*)d_in[10];
    const float* nbm    = (const float*)d_in[11];
    const float* lnfg   = (const float*)d_in[12];
    const float* lnfb   = (const float*)d_in[13];
    const float* headw  = (const float*)d_in[14];
    float* out = (float*)d_out;
    (void)in_sizes; (void)n_in; (void)out_size;

    size_t off = 0;
    auto alloc = [&](size_t bytes) {
        void* p = (char*)d_ws + off;
        off += (bytes + 255) & ~(size_t)255;
        return p;
    };
    float*    x   = (float*)alloc((size_t)BT * DM * 4);
    float*    ev  = (float*)alloc((size_t)BT * DM * 4);
    ushort_t* NB  = (ushort_t*)alloc((size_t)BT * K1 * 2);
    ushort_t* W1t = (ushort_t*)alloc((size_t)NR * H2 * K1 * 2);
    ushort_t* W2t = (ushort_t*)alloc((size_t)DM * NR * H2 * 2);
    ushort_t* HWt = (ushort_t*)alloc((size_t)VSZ * DM * 2);
    ushort_t* Xf  = (ushort_t*)alloc((size_t)BT * DM * 2);
    float*    rw  = (float*)alloc((size_t)T_SEQ * NR * 4);

    size_t Hcap = (ws_size > off) ? (ws_size - off) : 0;
    int chunkR = (int)(Hcap / ((size_t)BT * H2 * 2));
    if (chunkR > 4) chunkR = 4;
    if (chunkR < 1) chunkR = 1;
    ushort_t* H = (ushort_t*)alloc((size_t)chunkR * BT * H2 * 2);

    // --- weight conversion / transpose (per call; ~200 MB traffic) ---
    transpose_f32_bf16<<<dim3(H2 / 32, K1 / 32, NR), dim3(32, 8), 0, stream>>>(
        w1, W1t, K1, H2, (long long)K1 * H2, (long long)H2 * K1, K1);
    transpose_f32_bf16<<<dim3(DM / 32, H2 / 32, NR), dim3(32, 8), 0, stream>>>(
        w2, W2t, H2, DM, (long long)H2 * DM, (long long)H2, NR * H2);
    transpose_f32_bf16<<<dim3(VSZ / 32, DM / 32, 1), dim3(32, 8), 0, stream>>>(
        headw, HWt, DM, VSZ, 0LL, 0LL, DM);

    // --- x = embed + pos; rule weights rw ---
    embed_pos<<<dim3(BT), dim3(256), 0, stream>>>(tokens, emb, pos, x);
    rw_kernel<<<dim3(T_SEQ), dim3(64), 0, stream>>>(gate, selw, selb, rw);

    // --- 5 CA steps ---
    for (int s = 0; s < NSTEP; ++s) {
        nb_build<<<dim3(BT), dim3(192), 0, stream>>>(x, NB);
        for (int r0 = 0; r0 < NR; r0 += chunkR) {
            int cr = imin_host(chunkR, NR - r0);
            int cn = cr * H2;
            gemm_bt<1><<<dim3(cn / 128, BT / 128), dim3(256), 0, stream>>>(
                NB, W1t + (size_t)r0 * H2 * K1, nullptr, H,
                BT, cn, K1, K1, K1, cn, b1, rw, r0 * H2, 0);
            gemm_bt<2><<<dim3(DM / 128, BT / 128), dim3(256), 0, stream>>>(
                H, W2t + (size_t)r0 * H2, ev, nullptr,
                BT, DM, cn, cn, NR * H2, DM, nullptr, nullptr, 0, r0 ? 1 : 0);
        }
        ln_kernel<0><<<dim3(BT), dim3(256), 0, stream>>>(
            x, ev, b2, rw, ng + s * DM, nbm + s * DM, x, nullptr);
    }

    // --- final LN -> bf16, head GEMM -> f32 out ---
    ln_kernel<1><<<dim3(BT), dim3(256), 0, stream>>>(
        x, nullptr, nullptr, nullptr, lnfg, lnfb, nullptr, Xf);
    gemm_bt<0><<<dim3(VSZ / 128, BT / 128), dim3(256), 0, stream>>>(
        Xf, HWt, out, nullptr, BT, VSZ, DM, DM, DM, VSZ,
        nullptr, nullptr, 0, 0);
}

// Round 2
// 2125.362 us; speedup vs baseline: 1.4735x; 1.4735x over previous
//
#include <hip/hip_runtime.h>

#define T_SEQ 2048
#define BT    8192
#define DM    512
#define NR    8
#define NSTEP 5
#define K1    1536   // 3*D
#define H2    1024   // 2*D
#define VSZ   32000
#define HN    8192   // NR*H2

using ushort_t = unsigned short;
using bf16x8 = __attribute__((ext_vector_type(8))) __bf16;
using f32x4  = __attribute__((ext_vector_type(4))) float;

__device__ __forceinline__ ushort_t f2bf(float f) {
    union { float f; unsigned u; } v; v.f = f;
    unsigned r = v.u + 0x7FFFu + ((v.u >> 16) & 1u);
    return (ushort_t)(r >> 16);
}

__device__ __forceinline__ void gload16(const void* g, void* l) {
    __builtin_amdgcn_global_load_lds((const __attribute__((address_space(1))) void*)g,
                                     (__attribute__((address_space(3))) void*)l, 16, 0, 0);
}

__device__ __forceinline__ float gelu_tanh(float x) {
    float x3 = x * x * x;
    float y  = 0.7978845608028654f * (x + 0.044715f * x3);
    float e  = __expf(-2.0f * fabsf(y));
    float th = (1.0f - e) / (1.0f + e);
    th = copysignf(th, y);
    return 0.5f * x * (1.0f + th);
}

#define BAR()    __builtin_amdgcn_s_barrier()
#define VMCNT4() asm volatile("s_waitcnt vmcnt(4)" ::: "memory")
#define VMCNT0() asm volatile("s_waitcnt vmcnt(0)" ::: "memory")

// transpose f32 src[z][K][N] -> bf16 dst[z*dstBatch + n*dstRow + k]
__global__ void transpose_f32_bf16(const float* __restrict__ src, ushort_t* __restrict__ dst,
                                   int K, int N, long long srcBatch, long long dstBatch, int dstRow)
{
    __shared__ float tile[32][33];
    src += (size_t)blockIdx.z * srcBatch;
    dst += (size_t)blockIdx.z * dstBatch;
    int n0 = blockIdx.x * 32, k0 = blockIdx.y * 32;
    int tx = threadIdx.x, ty = threadIdx.y;
    #pragma unroll
    for (int i = 0; i < 32; i += 8)
        tile[ty + i][tx] = src[(size_t)(k0 + ty + i) * N + (n0 + tx)];
    __syncthreads();
    #pragma unroll
    for (int i = 0; i < 32; i += 8)
        dst[(size_t)(n0 + ty + i) * dstRow + (k0 + tx)] = f2bf(tile[tx][ty + i]);
}

__global__ void embed_pos(const int* __restrict__ tokens, const float* __restrict__ emb,
                          const float* __restrict__ pos, float* __restrict__ x,
                          ushort_t* __restrict__ xbf)
{
    int row = blockIdx.x;
    int t = row & (T_SEQ - 1);
    int tok = tokens[row];
    int i = threadIdx.x;              // 256 threads * float2 = 512 floats
    float2 e = ((const float2*)(emb + (size_t)tok * DM))[i];
    float2 p = ((const float2*)(pos + (size_t)t * DM))[i];
    float2 v = make_float2(e.x + p.x, e.y + p.y);
    ((float2*)(x + (size_t)row * DM))[i] = v;
    ushort_t bb[2] = { f2bf(v.x), f2bf(v.y) };
    ((unsigned*)(xbf + (size_t)row * DM))[i] = *(const unsigned*)bb;
}

__global__ void rw_kernel(const float* __restrict__ gate, const float* __restrict__ selw,
                          const float* __restrict__ selb, float* __restrict__ rw)
{
    int t = blockIdx.x, lane = threadIdx.x;  // 64 lanes
    float p[NR];
    #pragma unroll
    for (int r = 0; r < NR; ++r) p[r] = 0.f;
    for (int d = lane; d < DM; d += 64) {
        float gv = gate[(size_t)t * DM + d] * 0.001f;
        const float* swr = selw + (size_t)d * NR;
        #pragma unroll
        for (int r = 0; r < NR; ++r) p[r] += gv * swr[r];
    }
    #pragma unroll
    for (int o = 32; o; o >>= 1) {
        #pragma unroll
        for (int r = 0; r < NR; ++r) p[r] += __shfl_down(p[r], o, 64);
    }
    if (lane == 0) {
        float mx = -1e30f;
        #pragma unroll
        for (int r = 0; r < NR; ++r) { p[r] += selb[r]; mx = fmaxf(mx, p[r]); }
        float s = 0.f;
        #pragma unroll
        for (int r = 0; r < NR; ++r) { p[r] = expf(p[r] - mx); s += p[r]; }
        float inv = 1.0f / s;
        #pragma unroll
        for (int r = 0; r < NR; ++r) rw[t * NR + r] = p[r] * inv;
    }
}

// FINAL=0: x = LN(x + sum_slices evp + sum_r rw*b2)*g + b -> xout f32 AND xbf
// FINAL=1: xbf = bf16(LN(x)*g + b)
template<int FINAL>
__global__ void ln_kernel(const float* __restrict__ xin, const float* __restrict__ evp,
                          const float* __restrict__ b2, const float* __restrict__ rwp,
                          const float* __restrict__ g, const float* __restrict__ b,
                          float* __restrict__ xout, ushort_t* __restrict__ xbf)
{
    __shared__ float sA[4], sB[4];
    int row = blockIdx.x, t = row & (T_SEQ - 1);
    int d = threadIdx.x << 1;
    float2 v = *(const float2*)(xin + (size_t)row * DM + d);
    float s0 = v.x, s1 = v.y;
    if (!FINAL) {
        #pragma unroll
        for (int sl = 0; sl < 4; ++sl) {
            float2 e = *(const float2*)(evp + ((size_t)sl * BT + row) * DM + d);
            s0 += e.x; s1 += e.y;
        }
        #pragma unroll
        for (int r = 0; r < NR; ++r) {
            float w = rwp[t * NR + r];
            s0 += w * b2[r * DM + d];
            s1 += w * b2[r * DM + d + 1];
        }
    }
    float sum = s0 + s1, sq = s0 * s0 + s1 * s1;
    #pragma unroll
    for (int o = 32; o; o >>= 1) {
        sum += __shfl_down(sum, o, 64);
        sq  += __shfl_down(sq, o, 64);
    }
    int w = threadIdx.x >> 6;
    if ((threadIdx.x & 63) == 0) { sA[w] = sum; sB[w] = sq; }
    __syncthreads();
    sum = sA[0] + sA[1] + sA[2] + sA[3];
    sq  = sB[0] + sB[1] + sB[2] + sB[3];
    float mean = sum * (1.0f / DM);
    float var  = sq * (1.0f / DM) - mean * mean;
    float rstd = rsqrtf(var + 1e-5f);
    float o0 = (s0 - mean) * rstd * g[d] + b[d];
    float o1 = (s1 - mean) * rstd * g[d + 1] + b[d + 1];
    ushort_t bb[2] = { f2bf(o0), f2bf(o1) };
    ((unsigned*)(xbf + (size_t)row * DM))[threadIdx.x] = *(const unsigned*)bb;
    if (!FINAL)
        *(float2*)(xout + (size_t)row * DM + d) = make_float2(o0, o1);
}

// ---------------------------------------------------------------------------
// 256x256 8-phase bf16 GEMM (BK=64, 8 waves, counted vmcnt, XOR k-slot swizzle)
// C[M,N] = A[M,K] @ Bt[N,K]^T.  AMODE 0: plain row-major A (lda).
// AMODE 1: A = xbf[BT][512], K=1536 synthesized via per-segment row roll.
// EPI 0: Cf[slice] = acc (f32, split-K slices).  EPI 1: Cb = bf16(gelu(acc+b1)*rw).
// ---------------------------------------------------------------------------
template<int EPI, int AMODE>
__global__ __launch_bounds__(512, 2)
void gemm8(const ushort_t* __restrict__ A, const ushort_t* __restrict__ Bt,
           float* __restrict__ Cf, ushort_t* __restrict__ Cb,
           int nTileN, int nPerSlice, int ktiles,
           int lda, int ldb, int ldc, long long sliceC,
           const float* __restrict__ bias, const float* __restrict__ rwp)
{
    __shared__ ushort_t As[2][256 * 64];
    __shared__ ushort_t Bs[2][256 * 64];

    const int tid  = threadIdx.x;
    const int wave = tid >> 6, lane = tid & 63;
    const int wm = wave >> 2, wn = wave & 3;

    // bijective XCD swizzle (m204)
    int nwg = gridDim.x, bid = blockIdx.x;
    int qq = nwg >> 3, rr = nwg & 7, xc = bid & 7, wi = bid >> 3;
    int wgid = (xc < rr ? xc * (qq + 1) : rr * (qq + 1) + (xc - rr) * qq) + wi;
    int slice = wgid / nPerSlice, rem = wgid - slice * nPerSlice;
    int tm = rem / nTileN, tn = rem - tm * nTileN;
    const int rowBase = tm * 256, colBase = tn * 256;
    const int kbase = slice * ktiles;
    if (EPI == 0) Cf += (long long)slice * sliceC;

    // staging geometry: lane -> row (lane>>3), phys k-slot (lane&7);
    // source k-slot pre-swizzled so reads XOR by (row&7).
    const int lr  = lane >> 3;
    const int skE = (((lane & 7) ^ (lr & 7)) << 3);
    const ushort_t* Bsrc = Bt + (size_t)(colBase + wave * 32 + lr) * ldb + skE;
    const ushort_t* Asrc = A + (size_t)(rowBase + wave * 32 + lr) * lda + skE;

    auto stageA = [&](int t) {
        ushort_t* d = &As[t & 1][wave * 32 * 64];
        if (AMODE == 0) {
            const ushort_t* s = Asrc + (size_t)(kbase + t) * 64;
            #pragma unroll
            for (int j = 0; j < 4; ++j)
                gload16(s + (size_t)(j * 8) * lda, d + j * 512);
        } else {
            int seg  = t >> 3;                                   // 8 k-tiles per 512-segment
            int dts  = (seg == 0) ? 0 : (seg == 1 ? (T_SEQ - 1) : 1);
            int colE = ((t & 7) << 6) + skE;
            #pragma unroll
            for (int j = 0; j < 4; ++j) {
                int gr = rowBase + wave * 32 + j * 8 + lr;
                int sr = (gr & ~(T_SEQ - 1)) | ((gr + dts) & (T_SEQ - 1));
                gload16(A + (size_t)sr * DM + colE, d + j * 512);
            }
        }
    };
    auto stageB = [&](int t) {
        ushort_t* d = &Bs[t & 1][wave * 32 * 64];
        const ushort_t* s = Bsrc + (size_t)(kbase + t) * 64;
        #pragma unroll
        for (int j = 0; j < 4; ++j)
            gload16(s + (size_t)(j * 8) * ldb, d + j * 512);
    };

    // MFMA fragment read geometry
    const int l15 = lane & 15;
    const int sl0 = (((lane >> 4) ^ (lane & 7))) << 3;       // kstep0 slot offset (elems)
    const int sl1 = (((lane >> 4) + 4) ^ (lane & 7)) << 3;   // kstep1
    const int aoff = (wm * 128 + l15) * 64;
    const int boff = (wn * 64 + l15) * 64;

    f32x4 acc[8][4] = {};
    bf16x8 Ar[2][4];        // current mh: [kstep][m]
    bf16x8 Br[2][2][2];     // [nh][kstep][n] (both nh kept)

    auto readA = [&](int buf, int mh) {
        #pragma unroll
        for (int m = 0; m < 4; ++m) {
            int base = aoff + mh * 4096 + m * 1024;
            Ar[0][m] = *(const bf16x8*)&As[buf][base + sl0];
            Ar[1][m] = *(const bf16x8*)&As[buf][base + sl1];
        }
    };
    auto readB = [&](int buf, int nh) {
        #pragma unroll
        for (int n = 0; n < 2; ++n) {
            int base = boff + nh * 2048 + n * 1024;
            Br[nh][0][n] = *(const bf16x8*)&Bs[buf][base + sl0];
            Br[nh][1][n] = *(const bf16x8*)&Bs[buf][base + sl1];
        }
    };
    auto mmaQ = [&](int mh, int nh) {
        __builtin_amdgcn_s_setprio(1);
        #pragma unroll
        for (int k = 0; k < 2; ++k)
            #pragma unroll
            for (int m = 0; m < 4; ++m)
                #pragma unroll
                for (int n = 0; n < 2; ++n)
                    acc[mh * 4 + m][nh * 2 + n] = __builtin_amdgcn_mfma_f32_16x16x32_bf16(
                        Ar[k][m], Br[nh][k][n], acc[mh * 4 + m][nh * 2 + n], 0, 0, 0);
        __builtin_amdgcn_s_setprio(0);
    };

    // prologue: stage tile0 (A+B) and tile1's A; wait tile0 landed (leave 4 in flight)
    stageA(0); stageB(0); stageA(1);
    VMCNT4();
    BAR();

    for (int t = 0; t < ktiles; ++t) {
        const int cur = t & 1;
        // phase 1: quadrant (0,0); stage B(t+1) -> Bs[cur^1] (safe: != read buf)
        readA(cur, 0); readB(cur, 0);
        if (t + 1 < ktiles) stageB(t + 1);
        BAR(); mmaQ(0, 0); BAR();
        // phase 2: quadrant (0,1)
        readB(cur, 1);
        BAR(); mmaQ(0, 1); BAR();
        // phase 3: quadrant (1,1)
        readA(cur, 1);
        BAR(); mmaQ(1, 1); BAR();
        // phase 4: quadrant (1,0); stage A(t+2) -> As[cur]
        // (safe: issued after B2(ph3), by which all waves' As[cur] ds_reads completed)
        bool pre = (t + 2 < ktiles);
        if (pre) stageA(t + 2);
        BAR(); mmaQ(1, 0);
        if (pre) { VMCNT4(); } else { VMCNT0(); }   // tile t+1 fully landed
        BAR();
    }

    // epilogue
    const int cl = l15, rl = (lane >> 4) << 2;
    if constexpr (EPI == 0) {
        #pragma unroll
        for (int mf = 0; mf < 8; ++mf) {
            int gr = rowBase + wm * 128 + mf * 16 + rl;
            #pragma unroll
            for (int nf = 0; nf < 4; ++nf) {
                int gc = colBase + wn * 64 + nf * 16 + cl;
                #pragma unroll
                for (int i = 0; i < 4; ++i)
                    Cf[(size_t)(gr + i) * ldc + gc] = acc[mf][nf][i];
            }
        }
    } else {
        int r = (colBase + wn * 64) >> 10;   // 64-col span never crosses a rule boundary
        float bv[4];
        #pragma unroll
        for (int nf = 0; nf < 4; ++nf)
            bv[nf] = bias[r * H2 + ((colBase + wn * 64 + nf * 16 + cl) & (H2 - 1))];
        #pragma unroll
        for (int mf = 0; mf < 8; ++mf) {
            int gr = rowBase + wm * 128 + mf * 16 + rl;
            #pragma unroll
            for (int i = 0; i < 4; ++i) {
                float rwv = rwp[((gr + i) & (T_SEQ - 1)) * NR + r];
                #pragma unroll
                for (int nf = 0; nf < 4; ++nf) {
                    int gc = colBase + wn * 64 + nf * 16 + cl;
                    float v = acc[mf][nf][i] + bv[nf];
                    v = gelu_tanh(v) * rwv;
                    Cb[(size_t)(gr + i) * ldc + gc] = f2bf(v);
                }
            }
        }
    }
}

extern "C" void kernel_launch(void* const* d_in, const int* in_sizes, int n_in,
                              void* d_out, int out_size, void* d_ws, size_t ws_size,
                              hipStream_t stream)
{
    const int*   tokens = (const int*)d_in[0];
    const float* gate   = (const float*)d_in[1];
    const float* emb    = (const float*)d_in[2];
    const float* pos    = (const float*)d_in[3];
    const float* w1     = (const float*)d_in[4];
    const float* b1     = (const float*)d_in[5];
    const float* w2     = (const float*)d_in[6];
    const float* b2     = (const float*)d_in[7];
    const float* selw   = (const float*)d_in[8];
    const float* selb   = (const float*)d_in[9];
    const float* ng     = (const float*)d_in[10];
    const float* nbm    = (const float*)d_in[11];
    const float* lnfg   = (const float*)d_in[12];
    const float* lnfb   = (const float*)d_in[13];
    const float* headw  = (const float*)d_in[14];
    float* out = (float*)d_out;
    (void)in_sizes; (void)n_in; (void)out_size; (void)ws_size;

    size_t off = 0;
    auto alloc = [&](size_t bytes) {
        void* p = (char*)d_ws + off;
        off += (bytes + 255) & ~(size_t)255;
        return p;
    };
    float*    x   = (float*)alloc((size_t)BT * DM * 4);
    ushort_t* xbf = (ushort_t*)alloc((size_t)BT * DM * 2);
    float*    evp = (float*)alloc((size_t)4 * BT * DM * 4);
    ushort_t* W1t = (ushort_t*)alloc((size_t)NR * H2 * K1 * 2);
    ushort_t* W2t = (ushort_t*)alloc((size_t)DM * HN * 2);
    ushort_t* HWt = (ushort_t*)alloc((size_t)VSZ * DM * 2);
    float*    rw  = (float*)alloc((size_t)T_SEQ * NR * 4);
    ushort_t* H   = (ushort_t*)alloc((size_t)BT * HN * 2);

    // --- weight conversion / transpose ---
    transpose_f32_bf16<<<dim3(H2 / 32, K1 / 32, NR), dim3(32, 8), 0, stream>>>(
        w1, W1t, K1, H2, (long long)K1 * H2, (long long)H2 * K1, K1);
    transpose_f32_bf16<<<dim3(DM / 32, H2 / 32, NR), dim3(32, 8), 0, stream>>>(
        w2, W2t, H2, DM, (long long)H2 * DM, (long long)H2, HN);
    transpose_f32_bf16<<<dim3(VSZ / 32, DM / 32, 1), dim3(32, 8), 0, stream>>>(
        headw, HWt, DM, VSZ, 0LL, 0LL, DM);

    // --- x = embed + pos (f32 + bf16); rule weights ---
    embed_pos<<<dim3(BT), dim3(256), 0, stream>>>(tokens, emb, pos, x, xbf);
    rw_kernel<<<dim3(T_SEQ), dim3(64), 0, stream>>>(gate, selw, selb, rw);

    // --- 5 CA steps ---
    for (int s = 0; s < NSTEP; ++s) {
        // GEMM1: H = bf16(gelu(NB @ W1 + b1) * rw), NB synthesized from xbf via roll
        gemm8<1, 1><<<dim3(1024), dim3(512), 0, stream>>>(
            xbf, W1t, nullptr, H, /*nTileN*/32, /*nPerSlice*/1024, /*ktiles*/K1 / 64,
            DM, K1, HN, 0LL, b1, rw);
        // GEMM2: evp[slice] = H @ W2 (split-K x4)
        gemm8<0, 0><<<dim3(256), dim3(512), 0, stream>>>(
            H, W2t, evp, nullptr, /*nTileN*/2, /*nPerSlice*/64, /*ktiles*/HN / 64 / 4,
            HN, HN, DM, (long long)BT * DM, nullptr, nullptr);
        ln_kernel<0><<<dim3(BT), dim3(256), 0, stream>>>(
            x, evp, b2, rw, ng + s * DM, nbm + s * DM, x, xbf);
    }

    // --- final LN -> bf16, head GEMM -> f32 out ---
    ln_kernel<1><<<dim3(BT), dim3(256), 0, stream>>>(
        x, nullptr, nullptr, nullptr, lnfg, lnfb, nullptr, xbf);
    gemm8<0, 0><<<dim3(4000), dim3(512), 0, stream>>>(
        xbf, HWt, out, nullptr, /*nTileN*/125, /*nPerSlice*/4000, /*ktiles*/DM / 64,
        DM, DM, VSZ, 0LL, nullptr, nullptr);
}

// Round 3
// 1987.989 us; speedup vs baseline: 1.5753x; 1.0691x over previous
//
#include <hip/hip_runtime.h>

#define T_SEQ 2048
#define BT    8192
#define DM    512
#define NR    8
#define NSTEP 5
#define K1    1536   // 3*D
#define H2    1024   // 2*D
#define VSZ   32000
#define HN    8192   // NR*H2

using ushort_t = unsigned short;
using bf16x8 = __attribute__((ext_vector_type(8))) __bf16;
using f32x4  = __attribute__((ext_vector_type(4))) float;

__device__ __forceinline__ ushort_t f2bf(float f) {
    union { float f; unsigned u; } v; v.f = f;
    unsigned r = v.u + 0x7FFFu + ((v.u >> 16) & 1u);
    return (ushort_t)(r >> 16);
}

__device__ __forceinline__ float bf2f(unsigned hi) {
    union { unsigned u; float f; } v; v.u = hi << 16;
    return v.f;
}

__device__ __forceinline__ void gload16(const void* g, void* l) {
    __builtin_amdgcn_global_load_lds((const __attribute__((address_space(1))) void*)g,
                                     (__attribute__((address_space(3))) void*)l, 16, 0, 0);
}

// gelu(tanh form) = x * sigmoid(x*(2.3022861 + 0.10294456*x^2))  [exact identity]
__device__ __forceinline__ float gelu_fast(float x) {
    float x2 = x * x;
    float u  = x * fmaf(x2, 0.10294456f, 2.3022861f);   // 2y*log2(e)
    float e  = exp2f(-u);
    return x * __builtin_amdgcn_rcpf(1.0f + e);
}

#define BAR()    __builtin_amdgcn_s_barrier()
#define VMCNT4() asm volatile("s_waitcnt vmcnt(4)" ::: "memory")
#define VMCNT0() asm volatile("s_waitcnt vmcnt(0)" ::: "memory")

// transpose f32 src[z][K][N] -> bf16 dst[z*dstBatch + n*dstRow + k]
__global__ void transpose_f32_bf16(const float* __restrict__ src, ushort_t* __restrict__ dst,
                                   int K, int N, long long srcBatch, long long dstBatch, int dstRow)
{
    __shared__ float tile[32][33];
    src += (size_t)blockIdx.z * srcBatch;
    dst += (size_t)blockIdx.z * dstBatch;
    int n0 = blockIdx.x * 32, k0 = blockIdx.y * 32;
    int tx = threadIdx.x, ty = threadIdx.y;
    #pragma unroll
    for (int i = 0; i < 32; i += 8)
        tile[ty + i][tx] = src[(size_t)(k0 + ty + i) * N + (n0 + tx)];
    __syncthreads();
    #pragma unroll
    for (int i = 0; i < 32; i += 8)
        dst[(size_t)(n0 + ty + i) * dstRow + (k0 + tx)] = f2bf(tile[tx][ty + i]);
}

__global__ void embed_pos(const int* __restrict__ tokens, const float* __restrict__ emb,
                          const float* __restrict__ pos, float* __restrict__ x,
                          ushort_t* __restrict__ xbf)
{
    int row = blockIdx.x;
    int t = row & (T_SEQ - 1);
    int tok = tokens[row];
    int i = threadIdx.x;              // 256 threads * float2 = 512 floats
    float2 e = ((const float2*)(emb + (size_t)tok * DM))[i];
    float2 p = ((const float2*)(pos + (size_t)t * DM))[i];
    float2 v = make_float2(e.x + p.x, e.y + p.y);
    ((float2*)(x + (size_t)row * DM))[i] = v;
    ushort_t bb[2] = { f2bf(v.x), f2bf(v.y) };
    ((unsigned*)(xbf + (size_t)row * DM))[i] = *(const unsigned*)bb;
}

__global__ void rw_kernel(const float* __restrict__ gate, const float* __restrict__ selw,
                          const float* __restrict__ selb, float* __restrict__ rw)
{
    int t = blockIdx.x, lane = threadIdx.x;  // 64 lanes
    float p[NR];
    #pragma unroll
    for (int r = 0; r < NR; ++r) p[r] = 0.f;
    for (int d = lane; d < DM; d += 64) {
        float gv = gate[(size_t)t * DM + d] * 0.001f;
        const float* swr = selw + (size_t)d * NR;
        #pragma unroll
        for (int r = 0; r < NR; ++r) p[r] += gv * swr[r];
    }
    #pragma unroll
    for (int o = 32; o; o >>= 1) {
        #pragma unroll
        for (int r = 0; r < NR; ++r) p[r] += __shfl_down(p[r], o, 64);
    }
    if (lane == 0) {
        float mx = -1e30f;
        #pragma unroll
        for (int r = 0; r < NR; ++r) { p[r] += selb[r]; mx = fmaxf(mx, p[r]); }
        float s = 0.f;
        #pragma unroll
        for (int r = 0; r < NR; ++r) { p[r] = expf(p[r] - mx); s += p[r]; }
        float inv = 1.0f / s;
        #pragma unroll
        for (int r = 0; r < NR; ++r) rw[t * NR + r] = p[r] * inv;
    }
}

// FINAL=0: x = LN(x + sum_slices evp(bf16) + sum_r rw*b2)*g + b -> xout f32 AND xbf
// FINAL=1: xbf = bf16(LN(x)*g + b)
template<int FINAL>
__global__ void ln_kernel(const float* __restrict__ xin, const ushort_t* __restrict__ evp,
                          const float* __restrict__ b2, const float* __restrict__ rwp,
                          const float* __restrict__ g, const float* __restrict__ b,
                          float* __restrict__ xout, ushort_t* __restrict__ xbf)
{
    __shared__ float sA[4], sB[4];
    int row = blockIdx.x, t = row & (T_SEQ - 1);
    int d = threadIdx.x << 1;
    float2 v = *(const float2*)(xin + (size_t)row * DM + d);
    float s0 = v.x, s1 = v.y;
    if (!FINAL) {
        #pragma unroll
        for (int sl = 0; sl < 4; ++sl) {
            unsigned u = ((const unsigned*)(evp + ((size_t)sl * BT + row) * DM))[threadIdx.x];
            s0 += bf2f(u & 0xffffu); s1 += bf2f(u >> 16);
        }
        #pragma unroll
        for (int r = 0; r < NR; ++r) {
            float w = rwp[t * NR + r];
            s0 += w * b2[r * DM + d];
            s1 += w * b2[r * DM + d + 1];
        }
    }
    float sum = s0 + s1, sq = s0 * s0 + s1 * s1;
    #pragma unroll
    for (int o = 32; o; o >>= 1) {
        sum += __shfl_down(sum, o, 64);
        sq  += __shfl_down(sq, o, 64);
    }
    int w = threadIdx.x >> 6;
    if ((threadIdx.x & 63) == 0) { sA[w] = sum; sB[w] = sq; }
    __syncthreads();
    sum = sA[0] + sA[1] + sA[2] + sA[3];
    sq  = sB[0] + sB[1] + sB[2] + sB[3];
    float mean = sum * (1.0f / DM);
    float var  = sq * (1.0f / DM) - mean * mean;
    float rstd = rsqrtf(var + 1e-5f);
    float o0 = (s0 - mean) * rstd * g[d] + b[d];
    float o1 = (s1 - mean) * rstd * g[d + 1] + b[d + 1];
    ushort_t bb[2] = { f2bf(o0), f2bf(o1) };
    ((unsigned*)(xbf + (size_t)row * DM))[threadIdx.x] = *(const unsigned*)bb;
    if (!FINAL)
        *(float2*)(xout + (size_t)row * DM + d) = make_float2(o0, o1);
}

// ---------------------------------------------------------------------------
// 256x256 8-phase bf16 GEMM (BK=64, 8 waves, counted vmcnt, XOR k-slot swizzle)
// C[M,N] = A[M,K] @ Bt[N,K]^T.  AMODE 0: plain row-major A (lda).
// AMODE 1: A = xbf[BT][512], K=1536 synthesized via per-segment row roll.
// FASTM 1: tm varies fastest over wgid (B-panel shared per XCD), else tn fastest.
// EPI 0: Cf[slice]=acc f32.  EPI 1: Cb=bf16(gelu(acc+b1)*rw).  EPI 2: Cb[slice]=bf16(acc).
// ---------------------------------------------------------------------------
template<int EPI, int AMODE, int FASTM>
__global__ __launch_bounds__(512, 2)
void gemm8(const ushort_t* __restrict__ A, const ushort_t* __restrict__ Bt,
           float* __restrict__ Cf, ushort_t* __restrict__ Cb,
           int nTileFast, int nPerSlice, int ktiles,
           int lda, int ldb, int ldc, long long sliceC,
           const float* __restrict__ bias, const float* __restrict__ rwp)
{
    __shared__ ushort_t As[2][256 * 64];
    __shared__ ushort_t Bs[2][256 * 64];

    const int tid  = threadIdx.x;
    const int wave = tid >> 6, lane = tid & 63;
    const int wm = wave >> 2, wn = wave & 3;

    // bijective XCD swizzle (m204)
    int nwg = gridDim.x, bid = blockIdx.x;
    int qq = nwg >> 3, rr = nwg & 7, xc = bid & 7, wi = bid >> 3;
    int wgid = (xc < rr ? xc * (qq + 1) : rr * (qq + 1) + (xc - rr) * qq) + wi;
    int slice = wgid / nPerSlice, rem = wgid - slice * nPerSlice;
    int tA = rem / nTileFast, tB = rem - tA * nTileFast;
    int tm = FASTM ? tB : tA, tn = FASTM ? tA : tB;
    const int rowBase = tm * 256, colBase = tn * 256;
    const int kbase = slice * ktiles;
    if (EPI == 0) Cf += (long long)slice * sliceC;
    if (EPI == 2) Cb += (long long)slice * sliceC;

    // staging geometry: lane -> row (lane>>3), phys k-slot (lane&7);
    // source k-slot pre-swizzled so reads XOR by (row&7).
    const int lr  = lane >> 3;
    const int skE = (((lane & 7) ^ (lr & 7)) << 3);
    const ushort_t* Bsrc = Bt + (size_t)(colBase + wave * 32 + lr) * ldb + skE;
    const ushort_t* Asrc = A + (size_t)(rowBase + wave * 32 + lr) * lda + skE;

    auto stageA = [&](int t) {
        ushort_t* d = &As[t & 1][wave * 32 * 64];
        if (AMODE == 0) {
            const ushort_t* s = Asrc + (size_t)(kbase + t) * 64;
            #pragma unroll
            for (int j = 0; j < 4; ++j)
                gload16(s + (size_t)(j * 8) * lda, d + j * 512);
        } else {
            int seg  = t >> 3;                                   // 8 k-tiles per 512-segment
            int dts  = (seg == 0) ? 0 : (seg == 1 ? (T_SEQ - 1) : 1);
            int colE = ((t & 7) << 6) + skE;
            #pragma unroll
            for (int j = 0; j < 4; ++j) {
                int gr = rowBase + wave * 32 + j * 8 + lr;
                int sr = (gr & ~(T_SEQ - 1)) | ((gr + dts) & (T_SEQ - 1));
                gload16(A + (size_t)sr * DM + colE, d + j * 512);
            }
        }
    };
    auto stageB = [&](int t) {
        ushort_t* d = &Bs[t & 1][wave * 32 * 64];
        const ushort_t* s = Bsrc + (size_t)(kbase + t) * 64;
        #pragma unroll
        for (int j = 0; j < 4; ++j)
            gload16(s + (size_t)(j * 8) * ldb, d + j * 512);
    };

    // MFMA fragment read geometry
    const int l15 = lane & 15;
    const int sl0 = (((lane >> 4) ^ (lane & 7))) << 3;       // kstep0 slot offset (elems)
    const int sl1 = (((lane >> 4) + 4) ^ (lane & 7)) << 3;   // kstep1
    const int aoff = (wm * 128 + l15) * 64;
    const int boff = (wn * 64 + l15) * 64;

    f32x4 acc[8][4] = {};
    bf16x8 Ar[2][4];        // current mh: [kstep][m]
    bf16x8 Br[2][2][2];     // [nh][kstep][n] (both nh kept)

    auto readA = [&](int buf, int mh) {
        #pragma unroll
        for (int m = 0; m < 4; ++m) {
            int base = aoff + mh * 4096 + m * 1024;
            Ar[0][m] = *(const bf16x8*)&As[buf][base + sl0];
            Ar[1][m] = *(const bf16x8*)&As[buf][base + sl1];
        }
    };
    auto readB = [&](int buf, int nh) {
        #pragma unroll
        for (int n = 0; n < 2; ++n) {
            int base = boff + nh * 2048 + n * 1024;
            Br[nh][0][n] = *(const bf16x8*)&Bs[buf][base + sl0];
            Br[nh][1][n] = *(const bf16x8*)&Bs[buf][base + sl1];
        }
    };
    auto mmaQ = [&](int mh, int nh) {
        __builtin_amdgcn_s_setprio(1);
        #pragma unroll
        for (int k = 0; k < 2; ++k)
            #pragma unroll
            for (int m = 0; m < 4; ++m)
                #pragma unroll
                for (int n = 0; n < 2; ++n)
                    acc[mh * 4 + m][nh * 2 + n] = __builtin_amdgcn_mfma_f32_16x16x32_bf16(
                        Ar[k][m], Br[nh][k][n], acc[mh * 4 + m][nh * 2 + n], 0, 0, 0);
        __builtin_amdgcn_s_setprio(0);
    };

    // prologue: stage tile0 (A+B) and tile1's A; wait tile0 landed (leave 4 in flight)
    stageA(0); stageB(0); stageA(1);
    VMCNT4();
    BAR();

    for (int t = 0; t < ktiles; ++t) {
        const int cur = t & 1;
        // phase 1: quadrant (0,0); stage B(t+1) -> Bs[cur^1] (safe: != read buf)
        readA(cur, 0); readB(cur, 0);
        if (t + 1 < ktiles) stageB(t + 1);
        BAR(); mmaQ(0, 0); BAR();
        // phase 2: quadrant (0,1)
        readB(cur, 1);
        BAR(); mmaQ(0, 1); BAR();
        // phase 3: quadrant (1,1)
        readA(cur, 1);
        BAR(); mmaQ(1, 1); BAR();
        // phase 4: quadrant (1,0); stage A(t+2) -> As[cur]
        // (safe: issued after ph3's closing BAR, by which all waves' As[cur] reads completed)
        bool pre = (t + 2 < ktiles);
        if (pre) stageA(t + 2);
        BAR(); mmaQ(1, 0);
        if (pre) { VMCNT4(); } else { VMCNT0(); }   // tile t+1 fully landed
        BAR();
    }

    // epilogue
    const int cl = l15, rl = (lane >> 4) << 2;
    if constexpr (EPI == 0) {
        #pragma unroll
        for (int mf = 0; mf < 8; ++mf) {
            int gr = rowBase + wm * 128 + mf * 16 + rl;
            #pragma unroll
            for (int nf = 0; nf < 4; ++nf) {
                int gc = colBase + wn * 64 + nf * 16 + cl;
                #pragma unroll
                for (int i = 0; i < 4; ++i)
                    Cf[(size_t)(gr + i) * ldc + gc] = acc[mf][nf][i];
            }
        }
    } else if constexpr (EPI == 2) {
        #pragma unroll
        for (int mf = 0; mf < 8; ++mf) {
            int gr = rowBase + wm * 128 + mf * 16 + rl;
            #pragma unroll
            for (int nf = 0; nf < 4; ++nf) {
                int gc = colBase + wn * 64 + nf * 16 + cl;
                #pragma unroll
                for (int i = 0; i < 4; ++i)
                    Cb[(size_t)(gr + i) * ldc + gc] = f2bf(acc[mf][nf][i]);
            }
        }
    } else {
        int r = (colBase + wn * 64) >> 10;   // 64-col span never crosses a rule boundary
        float bv[4];
        #pragma unroll
        for (int nf = 0; nf < 4; ++nf)
            bv[nf] = bias[r * H2 + ((colBase + wn * 64 + nf * 16 + cl) & (H2 - 1))];
        #pragma unroll
        for (int mf = 0; mf < 8; ++mf) {
            int gr = rowBase + wm * 128 + mf * 16 + rl;
            #pragma unroll
            for (int i = 0; i < 4; ++i) {
                float rwv = rwp[((gr + i) & (T_SEQ - 1)) * NR + r];
                #pragma unroll
                for (int nf = 0; nf < 4; ++nf) {
                    int gc = colBase + wn * 64 + nf * 16 + cl;
                    float v = acc[mf][nf][i] + bv[nf];
                    v = gelu_fast(v) * rwv;
                    Cb[(size_t)(gr + i) * ldc + gc] = f2bf(v);
                }
            }
        }
    }
}

extern "C" void kernel_launch(void* const* d_in, const int* in_sizes, int n_in,
                              void* d_out, int out_size, void* d_ws, size_t ws_size,
                              hipStream_t stream)
{
    const int*   tokens = (const int*)d_in[0];
    const float* gate   = (const float*)d_in[1];
    const float* emb    = (const float*)d_in[2];
    const float* pos    = (const float*)d_in[3];
    const float* w1     = (const float*)d_in[4];
    const float* b1     = (const float*)d_in[5];
    const float* w2     = (const float*)d_in[6];
    const float* b2     = (const float*)d_in[7];
    const float* selw   = (const float*)d_in[8];
    const float* selb   = (const float*)d_in[9];
    const float* ng     = (const float*)d_in[10];
    const float* nbm    = (const float*)d_in[11];
    const float* lnfg   = (const float*)d_in[12];
    const float* lnfb   = (const float*)d_in[13];
    const float* headw  = (const float*)d_in[14];
    float* out = (float*)d_out;
    (void)in_sizes; (void)n_in; (void)out_size; (void)ws_size;

    size_t off = 0;
    auto alloc = [&](size_t bytes) {
        void* p = (char*)d_ws + off;
        off += (bytes + 255) & ~(size_t)255;
        return p;
    };
    float*    x   = (float*)alloc((size_t)BT * DM * 4);
    ushort_t* xbf = (ushort_t*)alloc((size_t)BT * DM * 2);
    ushort_t* evp = (ushort_t*)alloc((size_t)4 * BT * DM * 2);
    ushort_t* W1t = (ushort_t*)alloc((size_t)NR * H2 * K1 * 2);
    ushort_t* W2t = (ushort_t*)alloc((size_t)DM * HN * 2);
    ushort_t* HWt = (ushort_t*)alloc((size_t)VSZ * DM * 2);
    float*    rw  = (float*)alloc((size_t)T_SEQ * NR * 4);
    ushort_t* H   = (ushort_t*)alloc((size_t)BT * HN * 2);

    // --- weight conversion / transpose ---
    transpose_f32_bf16<<<dim3(H2 / 32, K1 / 32, NR), dim3(32, 8), 0, stream>>>(
        w1, W1t, K1, H2, (long long)K1 * H2, (long long)H2 * K1, K1);
    transpose_f32_bf16<<<dim3(DM / 32, H2 / 32, NR), dim3(32, 8), 0, stream>>>(
        w2, W2t, H2, DM, (long long)H2 * DM, (long long)H2, HN);
    transpose_f32_bf16<<<dim3(VSZ / 32, DM / 32, 1), dim3(32, 8), 0, stream>>>(
        headw, HWt, DM, VSZ, 0LL, 0LL, DM);

    // --- x = embed + pos (f32 + bf16); rule weights ---
    embed_pos<<<dim3(BT), dim3(256), 0, stream>>>(tokens, emb, pos, x, xbf);
    rw_kernel<<<dim3(T_SEQ), dim3(64), 0, stream>>>(gate, selw, selb, rw);

    // --- 5 CA steps ---
    for (int s = 0; s < NSTEP; ++s) {
        // GEMM1: H = bf16(gelu(NB @ W1 + b1) * rw), NB synthesized from xbf via roll.
        // FASTM=1: concurrent blocks per XCD share a B-panel, stream xbf once.
        gemm8<1, 1, 1><<<dim3(1024), dim3(512), 0, stream>>>(
            xbf, W1t, nullptr, H, /*nTileFast(tm)*/32, /*nPerSlice*/1024, /*ktiles*/K1 / 64,
            DM, K1, HN, 0LL, b1, rw);
        // GEMM2: evp[slice] = bf16(H @ W2) (split-K x4)
        gemm8<2, 0, 0><<<dim3(256), dim3(512), 0, stream>>>(
            H, W2t, nullptr, evp, /*nTileFast(tn)*/2, /*nPerSlice*/64, /*ktiles*/HN / 64 / 4,
            HN, HN, DM, (long long)BT * DM, nullptr, nullptr);
        ln_kernel<0><<<dim3(BT), dim3(256), 0, stream>>>(
            x, evp, b2, rw, ng + s * DM, nbm + s * DM, x, xbf);
    }

    // --- final LN -> bf16, head GEMM -> f32 out ---
    ln_kernel<1><<<dim3(BT), dim3(256), 0, stream>>>(
        x, nullptr, nullptr, nullptr, lnfg, lnfb, nullptr, xbf);
    gemm8<0, 0, 0><<<dim3(4000), dim3(512), 0, stream>>>(
        xbf, HWt, out, nullptr, /*nTileFast(tn)*/125, /*nPerSlice*/4000, /*ktiles*/DM / 64,
        DM, DM, VSZ, 0LL, nullptr, nullptr);
}

// Round 4
// 1951.636 us; speedup vs baseline: 1.6046x; 1.0186x over previous
//
#include <hip/hip_runtime.h>

#define T_SEQ 2048
#define BT    8192
#define DM    512
#define NR    8
#define NSTEP 5
#define K1    1536   // 3*D
#define H2    1024   // 2*D
#define VSZ   32000
#define HN    8192   // NR*H2

using ushort_t = unsigned short;
using bf16x8 = __attribute__((ext_vector_type(8))) __bf16;
using f32x4  = __attribute__((ext_vector_type(4))) float;

__device__ __forceinline__ ushort_t f2bf(float f) {
    union { float f; unsigned u; } v; v.f = f;
    unsigned r = v.u + 0x7FFFu + ((v.u >> 16) & 1u);
    return (ushort_t)(r >> 16);
}

__device__ __forceinline__ float bf2f(unsigned hi) {
    union { unsigned u; float f; } v; v.u = hi << 16;
    return v.f;
}

__device__ __forceinline__ void gload16(const void* g, void* l) {
    __builtin_amdgcn_global_load_lds((const __attribute__((address_space(1))) void*)g,
                                     (__attribute__((address_space(3))) void*)l, 16, 0, 0);
}

// gelu(tanh form) = x * sigmoid(x*(2.3022861 + 0.10294456*x^2))  [exact identity]
__device__ __forceinline__ float gelu_fast(float x) {
    float x2 = x * x;
    float u  = x * fmaf(x2, 0.10294456f, 2.3022861f);   // 2y*log2(e)
    float e  = exp2f(-u);
    return x * __builtin_amdgcn_rcpf(1.0f + e);
}

#define BAR()    __builtin_amdgcn_s_barrier()
#define VMCNT4() asm volatile("s_waitcnt vmcnt(4)" ::: "memory")
#define VMCNT0() asm volatile("s_waitcnt vmcnt(0)" ::: "memory")

// transpose f32 src[z][K][N] -> bf16 dst[z*dstBatch + n*dstRow + k]
__global__ void transpose_f32_bf16(const float* __restrict__ src, ushort_t* __restrict__ dst,
                                   int K, int N, long long srcBatch, long long dstBatch, int dstRow)
{
    __shared__ float tile[32][33];
    src += (size_t)blockIdx.z * srcBatch;
    dst += (size_t)blockIdx.z * dstBatch;
    int n0 = blockIdx.x * 32, k0 = blockIdx.y * 32;
    int tx = threadIdx.x, ty = threadIdx.y;
    #pragma unroll
    for (int i = 0; i < 32; i += 8)
        tile[ty + i][tx] = src[(size_t)(k0 + ty + i) * N + (n0 + tx)];
    __syncthreads();
    #pragma unroll
    for (int i = 0; i < 32; i += 8)
        dst[(size_t)(n0 + ty + i) * dstRow + (k0 + tx)] = f2bf(tile[tx][ty + i]);
}

__global__ void embed_pos(const int* __restrict__ tokens, const float* __restrict__ emb,
                          const float* __restrict__ pos, float* __restrict__ x,
                          ushort_t* __restrict__ xbf)
{
    int row = blockIdx.x;
    int t = row & (T_SEQ - 1);
    int tok = tokens[row];
    int i = threadIdx.x;              // 256 threads * float2 = 512 floats
    float2 e = ((const float2*)(emb + (size_t)tok * DM))[i];
    float2 p = ((const float2*)(pos + (size_t)t * DM))[i];
    float2 v = make_float2(e.x + p.x, e.y + p.y);
    ((float2*)(x + (size_t)row * DM))[i] = v;
    ushort_t bb[2] = { f2bf(v.x), f2bf(v.y) };
    ((unsigned*)(xbf + (size_t)row * DM))[i] = *(const unsigned*)bb;
}

__global__ void rw_kernel(const float* __restrict__ gate, const float* __restrict__ selw,
                          const float* __restrict__ selb, float* __restrict__ rw)
{
    int t = blockIdx.x, lane = threadIdx.x;  // 64 lanes
    float p[NR];
    #pragma unroll
    for (int r = 0; r < NR; ++r) p[r] = 0.f;
    for (int d = lane; d < DM; d += 64) {
        float gv = gate[(size_t)t * DM + d] * 0.001f;
        const float* swr = selw + (size_t)d * NR;
        #pragma unroll
        for (int r = 0; r < NR; ++r) p[r] += gv * swr[r];
    }
    #pragma unroll
    for (int o = 32; o; o >>= 1) {
        #pragma unroll
        for (int r = 0; r < NR; ++r) p[r] += __shfl_down(p[r], o, 64);
    }
    if (lane == 0) {
        float mx = -1e30f;
        #pragma unroll
        for (int r = 0; r < NR; ++r) { p[r] += selb[r]; mx = fmaxf(mx, p[r]); }
        float s = 0.f;
        #pragma unroll
        for (int r = 0; r < NR; ++r) { p[r] = expf(p[r] - mx); s += p[r]; }
        float inv = 1.0f / s;
        #pragma unroll
        for (int r = 0; r < NR; ++r) rw[t * NR + r] = p[r] * inv;
    }
}

// FINAL=0: x = LN(x + sum_slices evp(bf16) + sum_r rw*b2)*g + b -> xout f32 AND xbf
// FINAL=1: xbf = bf16(LN(x)*g + b)
template<int FINAL>
__global__ void ln_kernel(const float* __restrict__ xin, const ushort_t* __restrict__ evp,
                          const float* __restrict__ b2, const float* __restrict__ rwp,
                          const float* __restrict__ g, const float* __restrict__ b,
                          float* __restrict__ xout, ushort_t* __restrict__ xbf)
{
    __shared__ float sA[4], sB[4];
    int row = blockIdx.x, t = row & (T_SEQ - 1);
    int d = threadIdx.x << 1;
    float2 v = *(const float2*)(xin + (size_t)row * DM + d);
    float s0 = v.x, s1 = v.y;
    if (!FINAL) {
        #pragma unroll
        for (int sl = 0; sl < 4; ++sl) {
            unsigned u = ((const unsigned*)(evp + ((size_t)sl * BT + row) * DM))[threadIdx.x];
            s0 += bf2f(u & 0xffffu); s1 += bf2f(u >> 16);
        }
        #pragma unroll
        for (int r = 0; r < NR; ++r) {
            float w = rwp[t * NR + r];
            s0 += w * b2[r * DM + d];
            s1 += w * b2[r * DM + d + 1];
        }
    }
    float sum = s0 + s1, sq = s0 * s0 + s1 * s1;
    #pragma unroll
    for (int o = 32; o; o >>= 1) {
        sum += __shfl_down(sum, o, 64);
        sq  += __shfl_down(sq, o, 64);
    }
    int w = threadIdx.x >> 6;
    if ((threadIdx.x & 63) == 0) { sA[w] = sum; sB[w] = sq; }
    __syncthreads();
    sum = sA[0] + sA[1] + sA[2] + sA[3];
    sq  = sB[0] + sB[1] + sB[2] + sB[3];
    float mean = sum * (1.0f / DM);
    float var  = sq * (1.0f / DM) - mean * mean;
    float rstd = rsqrtf(var + 1e-5f);
    float o0 = (s0 - mean) * rstd * g[d] + b[d];
    float o1 = (s1 - mean) * rstd * g[d + 1] + b[d + 1];
    ushort_t bb[2] = { f2bf(o0), f2bf(o1) };
    ((unsigned*)(xbf + (size_t)row * DM))[threadIdx.x] = *(const unsigned*)bb;
    if (!FINAL)
        *(float2*)(xout + (size_t)row * DM + d) = make_float2(o0, o1);
}

// ---------------------------------------------------------------------------
// 256x256 bf16 GEMM, BK=64, 8 waves. 3-phase schedule per K-tile:
//   P1: read ALL A frags + B(nh0) | stage B(t+1)  -> 16 MFMA (0,0)
//   P2: read B(nh1)               | stage A(t+2)  -> 16 MFMA (0,1)
//   P3: pure 32-MFMA cluster (1,1)+(1,0), counted vmcnt(4), barrier
// Steady-state outstanding at tile end: {A(t+1),B(t+1),A(t+2)} = 12 -> vmcnt(4)
// retires A(t+1),B(t+1). Tail tiles (no staging) drain with vmcnt(0).
// C[M,N] = A[M,K] @ Bt[N,K]^T.  AMODE 1: A = xbf[BT][512], K=1536 via row roll.
// FASTM 1: tm fastest (B-panel shared per XCD).
// EPI 0: Cf[slice]=acc f32.  EPI 1: Cb=bf16(gelu(acc+b1)*rw).  EPI 2: Cb[slice]=bf16(acc).
// ---------------------------------------------------------------------------
template<int EPI, int AMODE, int FASTM>
__global__ __launch_bounds__(512, 2)
void gemm8(const ushort_t* __restrict__ A, const ushort_t* __restrict__ Bt,
           float* __restrict__ Cf, ushort_t* __restrict__ Cb,
           int nTileFast, int nPerSlice, int ktiles,
           int lda, int ldb, int ldc, long long sliceC,
           const float* __restrict__ bias, const float* __restrict__ rwp)
{
    __shared__ ushort_t As[2][256 * 64];
    __shared__ ushort_t Bs[2][256 * 64];

    const int tid  = threadIdx.x;
    const int wave = tid >> 6, lane = tid & 63;
    const int wm = wave >> 2, wn = wave & 3;

    // bijective XCD swizzle (m204)
    int nwg = gridDim.x, bid = blockIdx.x;
    int qq = nwg >> 3, rr = nwg & 7, xc = bid & 7, wi = bid >> 3;
    int wgid = (xc < rr ? xc * (qq + 1) : rr * (qq + 1) + (xc - rr) * qq) + wi;
    int slice = wgid / nPerSlice, rem = wgid - slice * nPerSlice;
    int tA = rem / nTileFast, tB = rem - tA * nTileFast;
    int tm = FASTM ? tB : tA, tn = FASTM ? tA : tB;
    const int rowBase = tm * 256, colBase = tn * 256;
    const int kbase = slice * ktiles;
    if (EPI == 0) Cf += (long long)slice * sliceC;
    if (EPI == 2) Cb += (long long)slice * sliceC;

    // staging geometry: lane -> row (lane>>3), phys k-slot (lane&7);
    // source k-slot pre-swizzled so reads XOR by (row&7).
    const int lr  = lane >> 3;
    const int skE = (((lane & 7) ^ (lr & 7)) << 3);
    const ushort_t* Bsrc = Bt + (size_t)(colBase + wave * 32 + lr) * ldb + skE;
    const ushort_t* Asrc = A + (size_t)(rowBase + wave * 32 + lr) * lda + skE;

    auto stageA = [&](int t) {
        ushort_t* d = &As[t & 1][wave * 32 * 64];
        if (AMODE == 0) {
            const ushort_t* s = Asrc + (size_t)(kbase + t) * 64;
            #pragma unroll
            for (int j = 0; j < 4; ++j)
                gload16(s + (size_t)(j * 8) * lda, d + j * 512);
        } else {
            int seg  = t >> 3;                                   // 8 k-tiles per 512-segment
            int dts  = (seg == 0) ? 0 : (seg == 1 ? (T_SEQ - 1) : 1);
            int colE = ((t & 7) << 6) + skE;
            #pragma unroll
            for (int j = 0; j < 4; ++j) {
                int gr = rowBase + wave * 32 + j * 8 + lr;
                int sr = (gr & ~(T_SEQ - 1)) | ((gr + dts) & (T_SEQ - 1));
                gload16(A + (size_t)sr * DM + colE, d + j * 512);
            }
        }
    };
    auto stageB = [&](int t) {
        ushort_t* d = &Bs[t & 1][wave * 32 * 64];
        const ushort_t* s = Bsrc + (size_t)(kbase + t) * 64;
        #pragma unroll
        for (int j = 0; j < 4; ++j)
            gload16(s + (size_t)(j * 8) * ldb, d + j * 512);
    };

    // MFMA fragment read geometry
    const int l15 = lane & 15;
    const int sl0 = (((lane >> 4) ^ (lane & 7))) << 3;       // kstep0 slot offset (elems)
    const int sl1 = (((lane >> 4) + 4) ^ (lane & 7)) << 3;   // kstep1
    const int aoff = (wm * 128 + l15) * 64;
    const int boff = (wn * 64 + l15) * 64;

    f32x4 acc[8][4] = {};
    bf16x8 Ar[2][2][4];     // [mh][kstep][m] — full tile's A frags
    bf16x8 Br[2][2][2];     // [nh][kstep][n]

    auto readAall = [&](int buf) {
        #pragma unroll
        for (int mh = 0; mh < 2; ++mh)
            #pragma unroll
            for (int m = 0; m < 4; ++m) {
                int base = aoff + mh * 4096 + m * 1024;
                Ar[mh][0][m] = *(const bf16x8*)&As[buf][base + sl0];
                Ar[mh][1][m] = *(const bf16x8*)&As[buf][base + sl1];
            }
    };
    auto readB = [&](int buf, int nh) {
        #pragma unroll
        for (int n = 0; n < 2; ++n) {
            int base = boff + nh * 2048 + n * 1024;
            Br[nh][0][n] = *(const bf16x8*)&Bs[buf][base + sl0];
            Br[nh][1][n] = *(const bf16x8*)&Bs[buf][base + sl1];
        }
    };
    auto mmaQ = [&](int mh, int nh) {
        #pragma unroll
        for (int k = 0; k < 2; ++k)
            #pragma unroll
            for (int m = 0; m < 4; ++m)
                #pragma unroll
                for (int n = 0; n < 2; ++n)
                    acc[mh * 4 + m][nh * 2 + n] = __builtin_amdgcn_mfma_f32_16x16x32_bf16(
                        Ar[mh][k][m], Br[nh][k][n], acc[mh * 4 + m][nh * 2 + n], 0, 0, 0);
    };

    // prologue: stage tile0 (A+B) and tile1's A; wait tile0 landed (leave A1 in flight)
    stageA(0); stageB(0);
    if (ktiles > 1) stageA(1);
    VMCNT4();
    BAR();

    for (int t = 0; t < ktiles; ++t) {
        const int cur = t & 1;
        // P1: all A frags + B(nh0); stage B(t+1) -> Bs[cur^1]
        readAall(cur); readB(cur, 0);
        if (t + 1 < ktiles) stageB(t + 1);
        BAR();
        __builtin_amdgcn_s_setprio(1); mmaQ(0, 0); __builtin_amdgcn_s_setprio(0);
        BAR();
        // P2: B(nh1); stage A(t+2) -> As[cur] (all As[cur] reads retired in P1)
        readB(cur, 1);
        bool pre = (t + 2 < ktiles);
        if (pre) stageA(t + 2);
        BAR();
        __builtin_amdgcn_s_setprio(1); mmaQ(0, 1); __builtin_amdgcn_s_setprio(0);
        BAR();
        // P3: pure MFMA cluster; counted vmcnt
        __builtin_amdgcn_s_setprio(1); mmaQ(1, 1); mmaQ(1, 0); __builtin_amdgcn_s_setprio(0);
        if (pre) { VMCNT4(); } else { VMCNT0(); }
        BAR();
    }

    // epilogue
    const int cl = l15, rl = (lane >> 4) << 2;
    if constexpr (EPI == 0) {
        #pragma unroll
        for (int mf = 0; mf < 8; ++mf) {
            int gr = rowBase + wm * 128 + mf * 16 + rl;
            #pragma unroll
            for (int nf = 0; nf < 4; ++nf) {
                int gc = colBase + wn * 64 + nf * 16 + cl;
                #pragma unroll
                for (int i = 0; i < 4; ++i)
                    Cf[(size_t)(gr + i) * ldc + gc] = acc[mf][nf][i];
            }
        }
    } else if constexpr (EPI == 2) {
        #pragma unroll
        for (int mf = 0; mf < 8; ++mf) {
            int gr = rowBase + wm * 128 + mf * 16 + rl;
            #pragma unroll
            for (int nf = 0; nf < 4; ++nf) {
                int gc = colBase + wn * 64 + nf * 16 + cl;
                #pragma unroll
                for (int i = 0; i < 4; ++i)
                    Cb[(size_t)(gr + i) * ldc + gc] = f2bf(acc[mf][nf][i]);
            }
        }
    } else {
        int r = (colBase + wn * 64) >> 10;   // 64-col span never crosses a rule boundary
        float bv[4];
        #pragma unroll
        for (int nf = 0; nf < 4; ++nf)
            bv[nf] = bias[r * H2 + ((colBase + wn * 64 + nf * 16 + cl) & (H2 - 1))];
        #pragma unroll
        for (int mf = 0; mf < 8; ++mf) {
            int gr = rowBase + wm * 128 + mf * 16 + rl;
            #pragma unroll
            for (int i = 0; i < 4; ++i) {
                float rwv = rwp[((gr + i) & (T_SEQ - 1)) * NR + r];
                #pragma unroll
                for (int nf = 0; nf < 4; ++nf) {
                    int gc = colBase + wn * 64 + nf * 16 + cl;
                    float v = acc[mf][nf][i] + bv[nf];
                    v = gelu_fast(v) * rwv;
                    Cb[(size_t)(gr + i) * ldc + gc] = f2bf(v);
                }
            }
        }
    }
}

extern "C" void kernel_launch(void* const* d_in, const int* in_sizes, int n_in,
                              void* d_out, int out_size, void* d_ws, size_t ws_size,
                              hipStream_t stream)
{
    const int*   tokens = (const int*)d_in[0];
    const float* gate   = (const float*)d_in[1];
    const float* emb    = (const float*)d_in[2];
    const float* pos    = (const float*)d_in[3];
    const float* w1     = (const float*)d_in[4];
    const float* b1     = (const float*)d_in[5];
    const float* w2     = (const float*)d_in[6];
    const float* b2     = (const float*)d_in[7];
    const float* selw   = (const float*)d_in[8];
    const float* selb   = (const float*)d_in[9];
    const float* ng     = (const float*)d_in[10];
    const float* nbm    = (const float*)d_in[11];
    const float* lnfg   = (const float*)d_in[12];
    const float* lnfb   = (const float*)d_in[13];
    const float* headw  = (const float*)d_in[14];
    float* out = (float*)d_out;
    (void)in_sizes; (void)n_in; (void)out_size; (void)ws_size;

    size_t off = 0;
    auto alloc = [&](size_t bytes) {
        void* p = (char*)d_ws + off;
        off += (bytes + 255) & ~(size_t)255;
        return p;
    };
    float*    x   = (float*)alloc((size_t)BT * DM * 4);
    ushort_t* xbf = (ushort_t*)alloc((size_t)BT * DM * 2);
    ushort_t* evp = (ushort_t*)alloc((size_t)4 * BT * DM * 2);
    ushort_t* W1t = (ushort_t*)alloc((size_t)NR * H2 * K1 * 2);
    ushort_t* W2t = (ushort_t*)alloc((size_t)DM * HN * 2);
    ushort_t* HWt = (ushort_t*)alloc((size_t)VSZ * DM * 2);
    float*    rw  = (float*)alloc((size_t)T_SEQ * NR * 4);
    ushort_t* H   = (ushort_t*)alloc((size_t)BT * HN * 2);

    // --- weight conversion / transpose ---
    transpose_f32_bf16<<<dim3(H2 / 32, K1 / 32, NR), dim3(32, 8), 0, stream>>>(
        w1, W1t, K1, H2, (long long)K1 * H2, (long long)H2 * K1, K1);
    transpose_f32_bf16<<<dim3(DM / 32, H2 / 32, NR), dim3(32, 8), 0, stream>>>(
        w2, W2t, H2, DM, (long long)H2 * DM, (long long)H2, HN);
    transpose_f32_bf16<<<dim3(VSZ / 32, DM / 32, 1), dim3(32, 8), 0, stream>>>(
        headw, HWt, DM, VSZ, 0LL, 0LL, DM);

    // --- x = embed + pos (f32 + bf16); rule weights ---
    embed_pos<<<dim3(BT), dim3(256), 0, stream>>>(tokens, emb, pos, x, xbf);
    rw_kernel<<<dim3(T_SEQ), dim3(64), 0, stream>>>(gate, selw, selb, rw);

    // --- 5 CA steps ---
    for (int s = 0; s < NSTEP; ++s) {
        // GEMM1: H = bf16(gelu(NB @ W1 + b1) * rw), NB synthesized from xbf via roll.
        // FASTM=1: concurrent blocks per XCD share a B-panel, stream xbf once.
        gemm8<1, 1, 1><<<dim3(1024), dim3(512), 0, stream>>>(
            xbf, W1t, nullptr, H, /*nTileFast(tm)*/32, /*nPerSlice*/1024, /*ktiles*/K1 / 64,
            DM, K1, HN, 0LL, b1, rw);
        // GEMM2: evp[slice] = bf16(H @ W2) (split-K x4)
        gemm8<2, 0, 0><<<dim3(256), dim3(512), 0, stream>>>(
            H, W2t, nullptr, evp, /*nTileFast(tn)*/2, /*nPerSlice*/64, /*ktiles*/HN / 64 / 4,
            HN, HN, DM, (long long)BT * DM, nullptr, nullptr);
        ln_kernel<0><<<dim3(BT), dim3(256), 0, stream>>>(
            x, evp, b2, rw, ng + s * DM, nbm + s * DM, x, xbf);
    }

    // --- final LN -> bf16, head GEMM -> f32 out ---
    ln_kernel<1><<<dim3(BT), dim3(256), 0, stream>>>(
        x, nullptr, nullptr, nullptr, lnfg, lnfb, nullptr, xbf);
    gemm8<0, 0, 0><<<dim3(4000), dim3(512), 0, stream>>>(
        xbf, HWt, out, nullptr, /*nTileFast(tn)*/125, /*nPerSlice*/4000, /*ktiles*/DM / 64,
        DM, DM, VSZ, 0LL, nullptr, nullptr);
}